// Round 1
// baseline (1232.552 us; speedup 1.0000x reference)
//
#include <hip/hip_runtime.h>
#include <stdint.h>

#define N_TILES (512*512)
#define K_TOP 1000
#define CAP 2048
#define DESC_CH_STRIDE ((size_t)2048*2048)

// ---- ws layout (bytes) ----
// valbits : 0        .. 1048576   u32[262144]
// args    : 1048576  .. 1310720   u8 [262144]
// hist    : 1310720  .. 1311744   u32[256]
// state   : 1311744  .. 1311776   u32[2]  (prefix, k_remaining)
// nsel    : 1311776  .. 1311780   u32
// sel     : 1311808  .. 1320000   u32[2048]
// pixidx  : 1320000  .. 1324000   u32[1000]

__global__ __launch_bounds__(256) void init_kernel(uint32_t* hist, uint32_t* nsel) {
    hist[threadIdx.x] = 0;
    if (threadIdx.x == 0) *nsel = 0;
}

// One thread per 4x4 tile: border-masked max + first-occurrence argmax.
// Fuses radix pass 0 (bits 31:24) histogram.
__global__ __launch_bounds__(256) void tile_kernel(const float* __restrict__ s,
        uint32_t* __restrict__ valbits, uint8_t* __restrict__ args,
        uint32_t* __restrict__ hist) {
    __shared__ uint32_t h[256];
    h[threadIdx.x] = 0;
    __syncthreads();

    int t  = blockIdx.x * 256 + threadIdx.x;   // 1024 blocks -> 262144 tiles
    int ty = t >> 9, tx = t & 511;
    int r0 = ty * 4, c0 = tx * 4;

    float best = -1.0f; int bk = 0;
    #pragma unroll
    for (int ky = 0; ky < 4; ++ky) {
        int r = r0 + ky;
        float4 q = *(const float4*)(s + (size_t)r * 2048 + c0);
        float vv[4] = {q.x, q.y, q.z, q.w};
        bool rok = (r >= 3) && (r < 2046);
        #pragma unroll
        for (int kx = 0; kx < 4; ++kx) {
            int c = c0 + kx;
            float v = (rok && c >= 3 && c < 2046) ? vv[kx] : 0.0f;
            if (v > best) { best = v; bk = ky * 4 + kx; }  // strictly > => first occurrence
        }
    }
    uint32_t vb = __float_as_uint(best);   // all vals >= +0.0 -> uint order == float order
    valbits[t] = vb;
    args[t]    = (uint8_t)bk;
    atomicAdd(&h[vb >> 24], 1u);
    __syncthreads();
    if (h[threadIdx.x]) atomicAdd(&hist[threadIdx.x], h[threadIdx.x]);
}

// Radix-select scan: find digit where cumulative-from-top crosses k. Resets hist.
__global__ __launch_bounds__(256) void scan_pass(uint32_t* __restrict__ hist,
        uint32_t* __restrict__ state, int pass) {
    __shared__ uint32_t h[256];
    int t = threadIdx.x;
    h[t] = hist[t];
    __syncthreads();
    uint32_t suf = 0;
    for (int j = t + 1; j < 256; ++j) suf += h[j];   // G(t) = count of digits > t
    uint32_t k      = (pass == 0) ? (uint32_t)K_TOP : state[1];
    uint32_t prefix = (pass == 0) ? 0u : state[0];
    __syncthreads();
    if (suf < k && suf + h[t] >= k) {                // unique crossing bin
        int shift = 24 - 8 * pass;
        state[0] = prefix | ((uint32_t)t << shift);
        state[1] = k - suf;
    }
    hist[t] = 0;                                     // ready for next pass
}

// Histogram of digit (bits shift+7 : shift) among elements matching prefix.
__global__ __launch_bounds__(256) void hist_pass(const uint32_t* __restrict__ valbits,
        uint32_t* __restrict__ hist, const uint32_t* __restrict__ state, int shift) {
    __shared__ uint32_t h[256];
    h[threadIdx.x] = 0;
    __syncthreads();
    uint32_t prefix = state[0];                      // bits >= shift+8 set, lower bits 0
    uint32_t pmask  = 0xFFFFFFFFu << (shift + 8);
    for (int i = blockIdx.x * 256 + threadIdx.x; i < N_TILES; i += 256 * 256) {
        uint32_t v = valbits[i];
        if ((v & pmask) == prefix)
            atomicAdd(&h[(v >> shift) & 0xFFu], 1u);
    }
    __syncthreads();
    if (h[threadIdx.x]) atomicAdd(&hist[threadIdx.x], h[threadIdx.x]);
}

// Compact indices of all elements with valbits >= V0 (count ~1000 + ties).
__global__ __launch_bounds__(256) void compact_pass(const uint32_t* __restrict__ valbits,
        const uint32_t* __restrict__ state, uint32_t* __restrict__ nsel,
        uint32_t* __restrict__ sel) {
    uint32_t V0 = state[0];
    for (int i = blockIdx.x * 256 + threadIdx.x; i < N_TILES; i += 256 * 256) {
        if (valbits[i] >= V0) {
            uint32_t pos = atomicAdd(nsel, 1u);
            if (pos < CAP) sel[pos] = (uint32_t)i;
        }
    }
}

// Single block: bitonic-sort u64 keys (valbits<<32 | idx) ascending; emit last 1000.
// This exactly reproduces jnp.argsort(vals)[-1000:] incl. stable tie-breaking.
__global__ __launch_bounds__(1024) void sort_emit(const uint32_t* __restrict__ valbits,
        const uint8_t* __restrict__ args, const uint32_t* __restrict__ nsel,
        const uint32_t* __restrict__ sel, float* __restrict__ out,
        uint32_t* __restrict__ pixidx) {
    __shared__ unsigned long long keys[CAP];
    int tid = threadIdx.x;
    uint32_t n = *nsel; if (n > CAP) n = CAP;
    for (int j = tid; j < CAP; j += 1024) {
        unsigned long long key = 0ULL;                // pad sorts to front
        if (j < (int)n) {
            uint32_t idx = sel[j];
            key = ((unsigned long long)valbits[idx] << 32) | idx;
        }
        keys[j] = key;
    }
    __syncthreads();
    for (int k = 2; k <= CAP; k <<= 1) {
        for (int jj = k >> 1; jj > 0; jj >>= 1) {
            for (int i = tid; i < CAP; i += 1024) {
                int ixj = i ^ jj;
                if (ixj > i) {
                    bool up = ((i & k) == 0);
                    unsigned long long a = keys[i], b = keys[ixj];
                    if ((a > b) == up) { keys[i] = b; keys[ixj] = a; }
                }
            }
            __syncthreads();
        }
    }
    for (int j = tid; j < K_TOP; j += 1024) {
        unsigned long long key = keys[CAP - K_TOP + j];
        uint32_t idx = (uint32_t)(key & 0xFFFFFFFFu);
        uint32_t vb  = (uint32_t)(key >> 32);
        int ty = (int)(idx >> 9), tx = (int)(idx & 511);
        int a  = args[idx];
        int row = ty * 4 + (a >> 2);
        int col = tx * 4 + (a & 3);
        out[2 * j]     = (float)col;                  // kpts[:,0] = col
        out[2 * j + 1] = (float)row;                  // kpts[:,1] = row
        out[2 * K_TOP + 64 * K_TOP + j] = __uint_as_float(vb);  // scores, bit-exact
        pixidx[j] = (uint32_t)(row * 2048 + col);
    }
}

// One wave (64 lanes) per keypoint: lane = channel; shuffle-reduce for L2 norm.
__global__ __launch_bounds__(256) void gather_desc(const float* __restrict__ desc,
        const uint32_t* __restrict__ pixidx, float* __restrict__ out) {
    int p    = blockIdx.x * 4 + (threadIdx.x >> 6);   // 250 blocks x 4 points
    int lane = threadIdx.x & 63;
    uint32_t pix = pixidx[p];
    float v  = desc[(size_t)lane * DESC_CH_STRIDE + pix];
    float ss = v * v;
    #pragma unroll
    for (int off = 32; off >= 1; off >>= 1) ss += __shfl_xor(ss, off, 64);
    out[2 * K_TOP + p * 64 + lane] = v / sqrtf(ss);
}

extern "C" void kernel_launch(void* const* d_in, const int* in_sizes, int n_in,
                              void* d_out, int out_size, void* d_ws, size_t ws_size,
                              hipStream_t stream) {
    const float* scores = (const float*)d_in[0];   // (1,1,2048,2048) f32
    const float* desc   = (const float*)d_in[1];   // (1,64,2048,2048) f32
    float* out = (float*)d_out;                    // [kpts 2000][desc 64000][scores 1000]
    char* ws = (char*)d_ws;

    uint32_t* valbits = (uint32_t*)(ws);
    uint8_t*  args    = (uint8_t*) (ws + 1048576);
    uint32_t* hist    = (uint32_t*)(ws + 1310720);
    uint32_t* state   = (uint32_t*)(ws + 1311744);
    uint32_t* nsel    = (uint32_t*)(ws + 1311776);
    uint32_t* sel     = (uint32_t*)(ws + 1311808);
    uint32_t* pixidx  = (uint32_t*)(ws + 1320000);

    init_kernel<<<1, 256, 0, stream>>>(hist, nsel);
    tile_kernel<<<1024, 256, 0, stream>>>(scores, valbits, args, hist);
    scan_pass<<<1, 256, 0, stream>>>(hist, state, 0);
    hist_pass<<<256, 256, 0, stream>>>(valbits, hist, state, 16);
    scan_pass<<<1, 256, 0, stream>>>(hist, state, 1);
    hist_pass<<<256, 256, 0, stream>>>(valbits, hist, state, 8);
    scan_pass<<<1, 256, 0, stream>>>(hist, state, 2);
    hist_pass<<<256, 256, 0, stream>>>(valbits, hist, state, 0);
    scan_pass<<<1, 256, 0, stream>>>(hist, state, 3);
    compact_pass<<<256, 256, 0, stream>>>(valbits, state, nsel, sel);
    sort_emit<<<1, 1024, 0, stream>>>(valbits, args, nsel, sel, out, pixidx);
    gather_desc<<<250, 256, 0, stream>>>(desc, pixidx, out);
}